// Round 1
// baseline (136.581 us; speedup 1.0000x reference)
//
#include <hip/hip_runtime.h>
#include <hip/hip_bf16.h>
#include <math.h>

#define N 4096
#define D 256
#define SCALEF 10.0f
#define EPSF 1e-5f
#define MARGIN_INTRA 40.0f
#define MARGIN_INTER 6.0f
// reference excludes sorted_intra[0:4] = diagonal + top-3 non-diag, sorted_inter[0:6]
#define LI 3
#define LX 6
#define NCHUNK 16   // j-chunks of 256
#define NSTRIP 32   // i-strips of 128
#define PPARTS (NCHUNK * 2)  // partial per (chunk, wr)

typedef unsigned short ushort_t;
typedef __attribute__((ext_vector_type(8))) short short8;
typedef __attribute__((ext_vector_type(4))) float floatx4;

__device__ __forceinline__ ushort_t f2bf(float x) {
    __hip_bfloat16 h = __float2bfloat16(x);
    return *reinterpret_cast<ushort_t*>(&h);
}
__device__ __forceinline__ float bf2f(ushort_t u) {
    __hip_bfloat16 h = *reinterpret_cast<__hip_bfloat16*>(&u);
    return __bfloat162float(h);
}

// Insert v into descending-sorted list t[0..L-1], keep top L.
// t0' = max(t0,v); tq' = med3(t[q-1], t[q], v)  -> L ops, depth-1 chain
// (vs 2L ops / depth-2L for the max/min bubble).
template <int L>
__device__ __forceinline__ void insert_desc(float (&t)[L], float v) {
    float top = fmaxf(t[0], v);
#pragma unroll
    for (int q = L - 1; q >= 1; --q)
        t[q] = __builtin_amdgcn_fmed3f(t[q - 1], t[q], v);
    t[0] = top;
}

// ---------------- Kernel 1: per-row sq, R, bf16 hi/lo split ----------------
__global__ __launch_bounds__(64) void prep_kernel(const float* __restrict__ F,
                                                  ushort_t* __restrict__ Fhi,
                                                  ushort_t* __restrict__ Flo,
                                                  float* __restrict__ sq,
                                                  float* __restrict__ Rrow) {
    int row = blockIdx.x;
    int lane = threadIdx.x;
    float4 v = ((const float4*)(F + (size_t)row * D))[lane];
    ushort4 h, l;
    h.x = f2bf(v.x); l.x = f2bf(v.x - bf2f(h.x));
    h.y = f2bf(v.y); l.y = f2bf(v.y - bf2f(h.y));
    h.z = f2bf(v.z); l.z = f2bf(v.z - bf2f(h.z));
    h.w = f2bf(v.w); l.w = f2bf(v.w - bf2f(h.w));
    ((ushort4*)(Fhi + (size_t)row * D))[lane] = h;
    ((ushort4*)(Flo + (size_t)row * D))[lane] = l;
    float s = v.x * v.x + v.y * v.y + v.z * v.z + v.w * v.w;
#pragma unroll
    for (int off = 32; off > 0; off >>= 1) s += __shfl_down(s, off, 64);
    if (lane == 0) {
        sq[row] = s;
        Rrow[row] = -SCALEF * sqrtf(2.0f * s);  // per-row exp reference shift
    }
}

// ---------------- Kernel 2: fused GEMM + online masked-topk-LSE ----------------
// Block: 128 rows (i) x 256 cols (j). Gram tile computed TRANSPOSED:
// MFMA A-operand <- j-features, B-operand <- i-features, so each lane's
// accumulator holds 4 rows (ni) x 16 cols. Per-lane state streams over j.
// LDST=34: 17-dword row stride (odd) -> fragment ds_read_b128 pattern
// (17*lane15 + 4*quad mod 32) is exactly 2-way (free); old 40 was 4-way.
#define LDST 34

// Epilogue for one finished 128(j)x(wave-tile) accumulation.
// Keys are k = x - R = fma(d, -SCALE, -R): monotone in x per row, one fma,
// and exp contribution is directly __expf(k).  HD: tile contains diagonal.
template <bool HD>
__device__ __forceinline__ void epi_tile(
    const floatx4 (&acc)[4][4], int j0, int wr, int quad,
    const float (&si)[4], const float (&nR4)[4], const int (&ci4)[4], const int (&ig)[4],
    const float* __restrict__ sq, const int* __restrict__ camid,
    float (&tI)[4][LI], float (&tX)[4][LX], float (&sIa)[4], float (&sXa)[4]) {
#pragma unroll
    for (int mi = 0; mi < 4; ++mi) {
        int jg0 = j0 + wr * 64 + mi * 16 + quad * 4;
        float4 sj4 = *(const float4*)(sq + jg0);
        int4 cj4 = *(const int4*)(camid + jg0);
        const float* sjp = (const float*)&sj4;
        const int* cjp = (const int*)&cj4;
#pragma unroll
        for (int ni = 0; ni < 4; ++ni) {
            int dd = jg0 - ig[ni];  // diagonal at r == -dd
            float sie = si[ni] + EPSF;
#pragma unroll
            for (int r = 0; r < 4; ++r) {
                float d2 = sie + sjp[r] - 2.0f * acc[mi][ni][r];
                float d = sqrtf(fmaxf(d2, 1e-12f));
                float k = fmaf(d, -SCALEF, nR4[ni]);  // x - R
                float e = __expf(k);
                bool ii = (cjp[r] == ci4[ni]);
                bool okI = HD ? (ii && ((dd + r) != 0)) : ii;
                sIa[ni] += okI ? e : 0.0f;
                sXa[ni] += ii ? 0.0f : e;
                insert_desc<LI>(tI[ni], okI ? k : -INFINITY);
                insert_desc<LX>(tX[ni], ii ? -INFINITY : k);
            }
        }
    }
}

__global__ __launch_bounds__(256, 2) void fused_kernel(
    const ushort_t* __restrict__ Fhi, const ushort_t* __restrict__ Flo,
    const float* __restrict__ sq, const float* __restrict__ Rrow,
    const int* __restrict__ camid,
    float4* __restrict__ partA, float4* __restrict__ partB, float4* __restrict__ partC) {
    __shared__ ushort_t lds[4][128 * LDST];  // Ajhi, Ajlo, Bihi, Bilo = 34816 B
    int tid = threadIdx.x;
    int wave = tid >> 6, lane = tid & 63;
    int wr = wave >> 1, wc = wave & 1;   // wr: j-half of tile, wc: i-half
    int lane15 = lane & 15, quad = lane >> 4;
    int cid = blockIdx.x, sid = blockIdx.y;
    int i0 = sid * 128, j00 = cid * 256;

    // per-lane row info (4 rows: ni = 0..3)
    float si[4], nR4[4];
    int ci4[4], ig[4];
#pragma unroll
    for (int ni = 0; ni < 4; ++ni) {
        int i = i0 + wc * 64 + ni * 16 + lane15;
        ig[ni] = i;
        si[ni] = sq[i];
        nR4[ni] = -Rrow[i];
        ci4[ni] = camid[i];
    }

    float tI[4][LI], tX[4][LX], sIa[4], sXa[4];
#pragma unroll
    for (int ni = 0; ni < 4; ++ni) {
#pragma unroll
        for (int q = 0; q < LI; ++q) tI[ni][q] = -INFINITY;
#pragma unroll
        for (int q = 0; q < LX; ++q) tX[ni][q] = -INFINITY;
        sIa[ni] = 0.0f; sXa[ni] = 0.0f;
    }

    int srow = tid >> 1, shalf = tid & 1;
    const ushort_t* gBh = Fhi + (size_t)(i0 + srow) * D + shalf * 16;
    const ushort_t* gBl = Flo + (size_t)(i0 + srow) * D + shalf * 16;
    ushort_t* sdst = &lds[0][0] + srow * LDST + shalf * 16;

    // Software-pipelined staging: regs for step t are written to LDS, then the
    // loads for step t+1 are ISSUED before the ds_read+MFMA phase of step t so
    // L2 latency hides under the MFMAs (and under the epilogue at jt boundary).
    short8 ra[2], rb[2], rc[2], rd[2];
    {
        const ushort_t* pAh = Fhi + (size_t)(j00 + srow) * D + shalf * 16;
        const ushort_t* pAl = Flo + (size_t)(j00 + srow) * D + shalf * 16;
#pragma unroll
        for (int q = 0; q < 2; ++q) {
            ra[q] = *(const short8*)(pAh + q * 8);
            rb[q] = *(const short8*)(pAl + q * 8);
            rc[q] = *(const short8*)(gBh + q * 8);
            rd[q] = *(const short8*)(gBl + q * 8);
        }
    }

    floatx4 acc[4][4];
#pragma unroll 1
    for (int t = 0; t < 16; ++t) {   // t = jt*8 + kt
        if ((t & 7) == 0) {
#pragma unroll
            for (int mi = 0; mi < 4; ++mi)
#pragma unroll
                for (int ni = 0; ni < 4; ++ni)
                    acc[mi][ni] = (floatx4){0.0f, 0.0f, 0.0f, 0.0f};
        }
        __syncthreads();   // previous step's ds_reads complete before overwrite
#pragma unroll
        for (int q = 0; q < 2; ++q) {
            *(short8*)(sdst + 0 * 128 * LDST + q * 8) = ra[q];
            *(short8*)(sdst + 1 * 128 * LDST + q * 8) = rb[q];
            *(short8*)(sdst + 2 * 128 * LDST + q * 8) = rc[q];
            *(short8*)(sdst + 3 * 128 * LDST + q * 8) = rd[q];
        }
        __syncthreads();

        if (t < 15) {   // prefetch step t+1 (WAR on ra..rd is safe: ds_write
                        // samples operands at issue, loads write back later)
            int tn = t + 1;
            int jtt = tn >> 3, ktt = tn & 7;
            const ushort_t* pAh = Fhi + (size_t)(j00 + jtt * 128 + srow) * D + shalf * 16 + ktt * 32;
            const ushort_t* pAl = Flo + (size_t)(j00 + jtt * 128 + srow) * D + shalf * 16 + ktt * 32;
            const ushort_t* pBh = gBh + ktt * 32;
            const ushort_t* pBl = gBl + ktt * 32;
#pragma unroll
            for (int q = 0; q < 2; ++q) {
                ra[q] = *(const short8*)(pAh + q * 8);
                rb[q] = *(const short8*)(pAl + q * 8);
                rc[q] = *(const short8*)(pBh + q * 8);
                rd[q] = *(const short8*)(pBl + q * 8);
            }
        }

        short8 ahi[4], alo[4], bhi[4], blo[4];
        int eoff = quad * 8;
#pragma unroll
        for (int mi = 0; mi < 4; ++mi) {
            int r = wr * 64 + mi * 16 + lane15;  // j-side rows
            ahi[mi] = *(const short8*)(&lds[0][0] + r * LDST + eoff);
            alo[mi] = *(const short8*)(&lds[1][0] + r * LDST + eoff);
        }
#pragma unroll
        for (int ni = 0; ni < 4; ++ni) {
            int r = wc * 64 + ni * 16 + lane15;  // i-side rows
            bhi[ni] = *(const short8*)(&lds[2][0] + r * LDST + eoff);
            blo[ni] = *(const short8*)(&lds[3][0] + r * LDST + eoff);
        }
#pragma unroll
        for (int mi = 0; mi < 4; ++mi)
#pragma unroll
            for (int ni = 0; ni < 4; ++ni) {
                acc[mi][ni] = __builtin_amdgcn_mfma_f32_16x16x32_bf16(ahi[mi], bhi[ni], acc[mi][ni], 0, 0, 0);
                acc[mi][ni] = __builtin_amdgcn_mfma_f32_16x16x32_bf16(ahi[mi], blo[ni], acc[mi][ni], 0, 0, 0);
                acc[mi][ni] = __builtin_amdgcn_mfma_f32_16x16x32_bf16(alo[mi], bhi[ni], acc[mi][ni], 0, 0, 0);
            }

        if ((t & 7) == 7) {
            int jtt = t >> 3;
            int j0 = j00 + jtt * 128;
            // diagonal lives in this 128-j subtile iff sid == 2*cid + jtt
            if (cid == (sid >> 1) && jtt == (sid & 1))
                epi_tile<true>(acc, j0, wr, quad, si, nR4, ci4, ig, sq, camid, tI, tX, sIa, sXa);
            else
                epi_tile<false>(acc, j0, wr, quad, si, nR4, ci4, ig, sq, camid, tI, tX, sIa, sXa);
        }
    }

    // merge across the 4 quads sharing each row (butterfly, offsets 16 & 32).
    // CRITICAL: snapshot ALL partner values BEFORE mutating own lists — lanes
    // run in lockstep, so interleaving shfl with insert reads corrupted state.
#pragma unroll
    for (int off = 16; off <= 32; off <<= 1) {
#pragma unroll
        for (int ni = 0; ni < 4; ++ni) {
            sIa[ni] += __shfl_xor(sIa[ni], off, 64);
            sXa[ni] += __shfl_xor(sXa[ni], off, 64);
            float oI[LI], oX[LX];
#pragma unroll
            for (int q = 0; q < LI; ++q) oI[q] = __shfl_xor(tI[ni][q], off, 64);
#pragma unroll
            for (int q = 0; q < LX; ++q) oX[q] = __shfl_xor(tX[ni][q], off, 64);
#pragma unroll
            for (int q = 0; q < LI; ++q) insert_desc<LI>(tI[ni], oI[q]);
#pragma unroll
            for (int q = 0; q < LX; ++q) insert_desc<LX>(tX[ni], oX[q]);
        }
    }

    if (quad == 0) {
        int p = cid * 2 + wr;
#pragma unroll
        for (int ni = 0; ni < 4; ++ni) {
            size_t idx = (size_t)p * N + ig[ni];
            partA[idx] = make_float4(tI[ni][0], tI[ni][1], tI[ni][2], sIa[ni]);
            partB[idx] = make_float4(tX[ni][0], tX[ni][1], tX[ni][2], tX[ni][3]);
            partC[idx] = make_float4(tX[ni][4], tX[ni][5], sXa[ni], 0.0f);
        }
    }
}

// ---------------- Kernel 3: merge partials -> per-row loss ----------------
// Stored list values are keys k = x - R, so exp contribution is __expf(k)
// directly; R re-enters only where needed (yI), and cancels in the inter hinge.
__global__ __launch_bounds__(256) void merge_kernel(const float4* __restrict__ partA,
                                                    const float4* __restrict__ partB,
                                                    const float4* __restrict__ partC,
                                                    const float* __restrict__ Rrow,
                                                    float* __restrict__ rowloss) {
    int row = blockIdx.x * 256 + threadIdx.x;
    float mI[LI] = {-INFINITY, -INFINITY, -INFINITY};
    float mX[LX] = {-INFINITY, -INFINITY, -INFINITY, -INFINITY, -INFINITY, -INFINITY};
    float SI = 0.0f, SX = 0.0f;
#pragma unroll 4
    for (int p = 0; p < PPARTS; ++p) {
        size_t idx = (size_t)p * N + row;
        float4 a = partA[idx];
        float4 b = partB[idx];
        float4 c = partC[idx];
        insert_desc<LI>(mI, a.x); insert_desc<LI>(mI, a.y); insert_desc<LI>(mI, a.z);
        SI += a.w;
        insert_desc<LX>(mX, b.x); insert_desc<LX>(mX, b.y);
        insert_desc<LX>(mX, b.z); insert_desc<LX>(mX, b.w);
        insert_desc<LX>(mX, c.x); insert_desc<LX>(mX, c.y);
        SX += c.z;
    }
    float R = Rrow[row];
    // intra: exclude diag (by construction) + top-3 values
    float subI = __expf(mI[0]) + __expf(mI[1]) + __expf(mI[2]);
    float restI = fmaxf(SI - subI, 1e-37f);
    float yI = R + logf(restI);
    float hI = fmaxf(yI + SCALEF * sqrtf(EPSF) + MARGIN_INTRA, 0.0f);  // -x0 = +10*sqrt(eps)
    // inter: exclude top-6 values; -x0 + yX = logf(restX) - mX[0]  (R cancels)
    float subX = __expf(mX[0]) + __expf(mX[1]) + __expf(mX[2]) +
                 __expf(mX[3]) + __expf(mX[4]) + __expf(mX[5]);
    float restX = fmaxf(SX - subX, 1e-37f);
    float hX = fmaxf(logf(restX) - mX[0] + MARGIN_INTER, 0.0f);
    rowloss[row] = hI + 0.5f * hX;
}

// ---------------- Kernel 4: final reduce ----------------
__global__ __launch_bounds__(256) void final_reduce(const float* __restrict__ rowloss,
                                                    float* __restrict__ out) {
    __shared__ float sbuf[256];
    int tid = threadIdx.x;
    float acc = 0.0f;
#pragma unroll
    for (int s = 0; s < 16; ++s) acc += rowloss[tid + s * 256];
    sbuf[tid] = acc;
    __syncthreads();
    for (int stride = 128; stride > 0; stride >>= 1) {
        if (tid < stride) sbuf[tid] += sbuf[tid + stride];
        __syncthreads();
    }
    if (tid == 0) out[0] = sbuf[0] * (1.0f / (float)N);
}

extern "C" void kernel_launch(void* const* d_in, const int* in_sizes, int n_in,
                              void* d_out, int out_size, void* d_ws, size_t ws_size,
                              hipStream_t stream) {
    const float* F = (const float*)d_in[0];
    const int* camid = (const int*)d_in[1];
    float* out = (float*)d_out;
    char* ws = (char*)d_ws;

    ushort_t* Fhi = (ushort_t*)ws;                               // 2 MB
    ushort_t* Flo = Fhi + (size_t)N * D;                         // 2 MB
    float* sq = (float*)(ws + 2 * (size_t)N * D * 2);            // 16 KB
    float* Rrow = sq + N;                                        // 16 KB
    float* rowloss = Rrow + N;                                   // 16 KB
    float4* partA = (float4*)(ws + 2 * (size_t)N * D * 2 + 3 * N * 4);  // 2 MB each
    float4* partB = partA + (size_t)PPARTS * N;
    float4* partC = partB + (size_t)PPARTS * N;

    prep_kernel<<<N, 64, 0, stream>>>(F, Fhi, Flo, sq, Rrow);
    fused_kernel<<<dim3(NCHUNK, NSTRIP), 256, 0, stream>>>(Fhi, Flo, sq, Rrow, camid,
                                                           partA, partB, partC);
    merge_kernel<<<N / 256, 256, 0, stream>>>(partA, partB, partC, Rrow, rowloss);
    final_reduce<<<1, 256, 0, stream>>>(rowloss, out);
}

// Round 2
// 120.156 us; speedup vs baseline: 1.1367x; 1.1367x over previous
//
#include <hip/hip_runtime.h>
#include <hip/hip_bf16.h>
#include <math.h>

#define N 4096
#define D 256
#define SCALEF 10.0f
#define EPSF 1e-5f
#define MARGIN_INTRA 40.0f
#define MARGIN_INTER 6.0f
// reference excludes sorted_intra[0:4] = diagonal + top-3 non-diag, sorted_inter[0:6]
#define LI 3
#define LX 6
#define NCHUNK 16   // j-chunks of 256
#define NSTRIP 32   // i-strips of 128
#define PPARTS (NCHUNK * 2)  // partial per (chunk, wr)

#define LOG2EF 1.44269504f
#define LN2F 0.69314718f

typedef unsigned short ushort_t;
typedef __attribute__((ext_vector_type(8))) short short8;
typedef __attribute__((ext_vector_type(4))) float floatx4;

__device__ __forceinline__ ushort_t f2bf(float x) {
    __hip_bfloat16 h = __float2bfloat16(x);
    return *reinterpret_cast<ushort_t*>(&h);
}
__device__ __forceinline__ float bf2f(ushort_t u) {
    __hip_bfloat16 h = *reinterpret_cast<__hip_bfloat16*>(&u);
    return __bfloat162float(h);
}

__device__ __forceinline__ float fast_exp2(float x) {
#if __has_builtin(__builtin_amdgcn_exp2f)
    return __builtin_amdgcn_exp2f(x);
#else
    return exp2f(x);
#endif
}

// Insert v into descending-sorted list t[0..L-1], keep top L.
// t0' = max(t0,v); tq' = med3(t[q-1], t[q], v)  -> L ops, depth-1 chain
// (vs 2L ops / depth-2L for the max/min bubble).
template <int L>
__device__ __forceinline__ void insert_desc(float (&t)[L], float v) {
    float top = fmaxf(t[0], v);
#pragma unroll
    for (int q = L - 1; q >= 1; --q)
        t[q] = __builtin_amdgcn_fmed3f(t[q - 1], t[q], v);
    t[0] = top;
}

// ---------------- Kernel 1: per-row sq, R, bf16 hi/lo split ----------------
__global__ __launch_bounds__(64) void prep_kernel(const float* __restrict__ F,
                                                  ushort_t* __restrict__ Fhi,
                                                  ushort_t* __restrict__ Flo,
                                                  float* __restrict__ sq,
                                                  float* __restrict__ Rrow) {
    int row = blockIdx.x;
    int lane = threadIdx.x;
    float4 v = ((const float4*)(F + (size_t)row * D))[lane];
    ushort4 h, l;
    h.x = f2bf(v.x); l.x = f2bf(v.x - bf2f(h.x));
    h.y = f2bf(v.y); l.y = f2bf(v.y - bf2f(h.y));
    h.z = f2bf(v.z); l.z = f2bf(v.z - bf2f(h.z));
    h.w = f2bf(v.w); l.w = f2bf(v.w - bf2f(h.w));
    ((ushort4*)(Fhi + (size_t)row * D))[lane] = h;
    ((ushort4*)(Flo + (size_t)row * D))[lane] = l;
    float s = v.x * v.x + v.y * v.y + v.z * v.z + v.w * v.w;
#pragma unroll
    for (int off = 32; off > 0; off >>= 1) s += __shfl_down(s, off, 64);
    if (lane == 0) {
        sq[row] = s;
        Rrow[row] = -SCALEF * sqrtf(2.0f * s);  // per-row exp reference shift
    }
}

// ---------------- Kernel 2: fused GEMM + online masked-topk-LSE ----------------
// Block: 128 rows (i) x 256 cols (j). Gram tile computed TRANSPOSED:
// MFMA A-operand <- j-features, B-operand <- i-features, so each lane's
// accumulator holds 4 rows (ni) x 16 cols. Per-lane state streams over j.
// LDST=40 (80 B): row starts stay 16B-aligned for short8 LDS ops -> single
// ds_{read,write}_b128 each.  (LDST=34 = 68 B regressed 1.7x: odd rows were
// only 4B-aligned, splitting every 16B LDS access.)
#define LDST 40

// Epilogue for one finished 128(j)x(wave-tile) accumulation.
// Keys are base-2: k2 = (x - R)*log2e = fma(d, -SCALE*log2e, -R*log2e).
// Monotone in x per row (same top-k membership); exp contribution is a single
// v_exp_f32: e = exp2(k2) = exp(x - R).  HD: tile contains the diagonal.
template <bool HD>
__device__ __forceinline__ void epi_tile(
    const floatx4 (&acc)[4][4], int j0, int wr, int quad,
    const float (&si)[4], const float (&nR2)[4], const int (&ci4)[4], const int (&ig)[4],
    const float* __restrict__ sq, const int* __restrict__ camid,
    float (&tI)[4][LI], float (&tX)[4][LX], float (&sIa)[4], float (&sXa)[4]) {
    const float C1 = -SCALEF * LOG2EF;
#pragma unroll
    for (int mi = 0; mi < 4; ++mi) {
        int jg0 = j0 + wr * 64 + mi * 16 + quad * 4;
        float4 sj4 = *(const float4*)(sq + jg0);
        int4 cj4 = *(const int4*)(camid + jg0);
        const float* sjp = (const float*)&sj4;
        const int* cjp = (const int*)&cj4;
#pragma unroll
        for (int ni = 0; ni < 4; ++ni) {
            int dd = jg0 - ig[ni];  // diagonal at r == -dd
            float sie = si[ni] + EPSF;
#pragma unroll
            for (int r = 0; r < 4; ++r) {
                float d2 = sie + sjp[r] - 2.0f * acc[mi][ni][r];
                float d = sqrtf(fmaxf(d2, 1e-12f));
                float k = fmaf(d, C1, nR2[ni]);  // (x - R) * log2e
                float e = fast_exp2(k);
                bool ii = (cjp[r] == ci4[ni]);
                bool okI = HD ? (ii && ((dd + r) != 0)) : ii;
                sIa[ni] += okI ? e : 0.0f;
                sXa[ni] += ii ? 0.0f : e;
                insert_desc<LI>(tI[ni], okI ? k : -INFINITY);
                insert_desc<LX>(tX[ni], ii ? -INFINITY : k);
            }
        }
    }
}

__global__ __launch_bounds__(256, 2) void fused_kernel(
    const ushort_t* __restrict__ Fhi, const ushort_t* __restrict__ Flo,
    const float* __restrict__ sq, const float* __restrict__ Rrow,
    const int* __restrict__ camid,
    float4* __restrict__ partA, float4* __restrict__ partB, float4* __restrict__ partC) {
    __shared__ ushort_t lds[4][128 * LDST];  // Ajhi, Ajlo, Bihi, Bilo = 40960 B
    int tid = threadIdx.x;
    int wave = tid >> 6, lane = tid & 63;
    int wr = wave >> 1, wc = wave & 1;   // wr: j-half of tile, wc: i-half
    int lane15 = lane & 15, quad = lane >> 4;
    int cid = blockIdx.x, sid = blockIdx.y;
    int i0 = sid * 128, j00 = cid * 256;

    // per-lane row info (4 rows: ni = 0..3)
    float si[4], nR2[4];
    int ci4[4], ig[4];
#pragma unroll
    for (int ni = 0; ni < 4; ++ni) {
        int i = i0 + wc * 64 + ni * 16 + lane15;
        ig[ni] = i;
        si[ni] = sq[i];
        nR2[ni] = -Rrow[i] * LOG2EF;
        ci4[ni] = camid[i];
    }

    float tI[4][LI], tX[4][LX], sIa[4], sXa[4];
#pragma unroll
    for (int ni = 0; ni < 4; ++ni) {
#pragma unroll
        for (int q = 0; q < LI; ++q) tI[ni][q] = -INFINITY;
#pragma unroll
        for (int q = 0; q < LX; ++q) tX[ni][q] = -INFINITY;
        sIa[ni] = 0.0f; sXa[ni] = 0.0f;
    }

    int srow = tid >> 1, shalf = tid & 1;
    const ushort_t* gBh = Fhi + (size_t)(i0 + srow) * D + shalf * 16;
    const ushort_t* gBl = Flo + (size_t)(i0 + srow) * D + shalf * 16;
    ushort_t* sdst = &lds[0][0] + srow * LDST + shalf * 16;

#pragma unroll 1
    for (int jt = 0; jt < 2; ++jt) {
        int j0 = j00 + jt * 128;
        const ushort_t* gAh = Fhi + (size_t)(j0 + srow) * D + shalf * 16;
        const ushort_t* gAl = Flo + (size_t)(j0 + srow) * D + shalf * 16;
        floatx4 acc[4][4] = {};

#pragma unroll 1
        for (int kt = 0; kt < 8; ++kt) {
            int koff = kt * 32;
            short8 ra[2], rb[2], rc[2], rd[2];
#pragma unroll
            for (int q = 0; q < 2; ++q) {
                ra[q] = *(const short8*)(gAh + koff + q * 8);
                rb[q] = *(const short8*)(gAl + koff + q * 8);
                rc[q] = *(const short8*)(gBh + koff + q * 8);
                rd[q] = *(const short8*)(gBl + koff + q * 8);
            }
            __syncthreads();
#pragma unroll
            for (int q = 0; q < 2; ++q) {
                *(short8*)(sdst + 0 * 128 * LDST + q * 8) = ra[q];
                *(short8*)(sdst + 1 * 128 * LDST + q * 8) = rb[q];
                *(short8*)(sdst + 2 * 128 * LDST + q * 8) = rc[q];
                *(short8*)(sdst + 3 * 128 * LDST + q * 8) = rd[q];
            }
            __syncthreads();

            short8 ahi[4], alo[4], bhi[4], blo[4];
            int eoff = quad * 8;
#pragma unroll
            for (int mi = 0; mi < 4; ++mi) {
                int r = wr * 64 + mi * 16 + lane15;  // j-side rows
                ahi[mi] = *(const short8*)(&lds[0][0] + r * LDST + eoff);
                alo[mi] = *(const short8*)(&lds[1][0] + r * LDST + eoff);
            }
#pragma unroll
            for (int ni = 0; ni < 4; ++ni) {
                int r = wc * 64 + ni * 16 + lane15;  // i-side rows
                bhi[ni] = *(const short8*)(&lds[2][0] + r * LDST + eoff);
                blo[ni] = *(const short8*)(&lds[3][0] + r * LDST + eoff);
            }
#pragma unroll
            for (int mi = 0; mi < 4; ++mi)
#pragma unroll
                for (int ni = 0; ni < 4; ++ni) {
                    acc[mi][ni] = __builtin_amdgcn_mfma_f32_16x16x32_bf16(ahi[mi], bhi[ni], acc[mi][ni], 0, 0, 0);
                    acc[mi][ni] = __builtin_amdgcn_mfma_f32_16x16x32_bf16(ahi[mi], blo[ni], acc[mi][ni], 0, 0, 0);
                    acc[mi][ni] = __builtin_amdgcn_mfma_f32_16x16x32_bf16(alo[mi], bhi[ni], acc[mi][ni], 0, 0, 0);
                }
        }

        // diagonal lives in this 128-j subtile iff cid == sid>>1 && jt == sid&1
        if (cid == (sid >> 1) && jt == (sid & 1))
            epi_tile<true>(acc, j0, wr, quad, si, nR2, ci4, ig, sq, camid, tI, tX, sIa, sXa);
        else
            epi_tile<false>(acc, j0, wr, quad, si, nR2, ci4, ig, sq, camid, tI, tX, sIa, sXa);
    }

    // merge across the 4 quads sharing each row (butterfly, offsets 16 & 32).
    // CRITICAL: snapshot ALL partner values BEFORE mutating own lists — lanes
    // run in lockstep, so interleaving shfl with insert reads corrupted state.
#pragma unroll
    for (int off = 16; off <= 32; off <<= 1) {
#pragma unroll
        for (int ni = 0; ni < 4; ++ni) {
            sIa[ni] += __shfl_xor(sIa[ni], off, 64);
            sXa[ni] += __shfl_xor(sXa[ni], off, 64);
            float oI[LI], oX[LX];
#pragma unroll
            for (int q = 0; q < LI; ++q) oI[q] = __shfl_xor(tI[ni][q], off, 64);
#pragma unroll
            for (int q = 0; q < LX; ++q) oX[q] = __shfl_xor(tX[ni][q], off, 64);
#pragma unroll
            for (int q = 0; q < LI; ++q) insert_desc<LI>(tI[ni], oI[q]);
#pragma unroll
            for (int q = 0; q < LX; ++q) insert_desc<LX>(tX[ni], oX[q]);
        }
    }

    if (quad == 0) {
        int p = cid * 2 + wr;
#pragma unroll
        for (int ni = 0; ni < 4; ++ni) {
            size_t idx = (size_t)p * N + ig[ni];
            partA[idx] = make_float4(tI[ni][0], tI[ni][1], tI[ni][2], sIa[ni]);
            partB[idx] = make_float4(tX[ni][0], tX[ni][1], tX[ni][2], tX[ni][3]);
            partC[idx] = make_float4(tX[ni][4], tX[ni][5], sXa[ni], 0.0f);
        }
    }
}

// ---------------- Kernel 3: merge partials -> per-row loss ----------------
// Stored list values are BASE-2 keys k2 = (x - R)*log2e, so exp contribution
// is exp2f(k2) = exp(x - R); natural-log re-enters via *LN2 where needed.
__global__ __launch_bounds__(256) void merge_kernel(const float4* __restrict__ partA,
                                                    const float4* __restrict__ partB,
                                                    const float4* __restrict__ partC,
                                                    const float* __restrict__ Rrow,
                                                    float* __restrict__ rowloss) {
    int row = blockIdx.x * 256 + threadIdx.x;
    float mI[LI] = {-INFINITY, -INFINITY, -INFINITY};
    float mX[LX] = {-INFINITY, -INFINITY, -INFINITY, -INFINITY, -INFINITY, -INFINITY};
    float SI = 0.0f, SX = 0.0f;
#pragma unroll 4
    for (int p = 0; p < PPARTS; ++p) {
        size_t idx = (size_t)p * N + row;
        float4 a = partA[idx];
        float4 b = partB[idx];
        float4 c = partC[idx];
        insert_desc<LI>(mI, a.x); insert_desc<LI>(mI, a.y); insert_desc<LI>(mI, a.z);
        SI += a.w;
        insert_desc<LX>(mX, b.x); insert_desc<LX>(mX, b.y);
        insert_desc<LX>(mX, b.z); insert_desc<LX>(mX, b.w);
        insert_desc<LX>(mX, c.x); insert_desc<LX>(mX, c.y);
        SX += c.z;
    }
    float R = Rrow[row];
    // intra: exclude diag (by construction) + top-3 values
    float subI = fast_exp2(mI[0]) + fast_exp2(mI[1]) + fast_exp2(mI[2]);
    float restI = fmaxf(SI - subI, 1e-37f);
    float yI = R + logf(restI);
    float hI = fmaxf(yI + SCALEF * sqrtf(EPSF) + MARGIN_INTRA, 0.0f);  // -x0 = +10*sqrt(eps)
    // inter: exclude top-6 values; -x0 + yX = logf(restX) - mX[0]*ln2  (R cancels)
    float subX = fast_exp2(mX[0]) + fast_exp2(mX[1]) + fast_exp2(mX[2]) +
                 fast_exp2(mX[3]) + fast_exp2(mX[4]) + fast_exp2(mX[5]);
    float restX = fmaxf(SX - subX, 1e-37f);
    float hX = fmaxf(logf(restX) - mX[0] * LN2F + MARGIN_INTER, 0.0f);
    rowloss[row] = hI + 0.5f * hX;
}

// ---------------- Kernel 4: final reduce ----------------
__global__ __launch_bounds__(256) void final_reduce(const float* __restrict__ rowloss,
                                                    float* __restrict__ out) {
    __shared__ float sbuf[256];
    int tid = threadIdx.x;
    float acc = 0.0f;
#pragma unroll
    for (int s = 0; s < 16; ++s) acc += rowloss[tid + s * 256];
    sbuf[tid] = acc;
    __syncthreads();
    for (int stride = 128; stride > 0; stride >>= 1) {
        if (tid < stride) sbuf[tid] += sbuf[tid + stride];
        __syncthreads();
    }
    if (tid == 0) out[0] = sbuf[0] * (1.0f / (float)N);
}

extern "C" void kernel_launch(void* const* d_in, const int* in_sizes, int n_in,
                              void* d_out, int out_size, void* d_ws, size_t ws_size,
                              hipStream_t stream) {
    const float* F = (const float*)d_in[0];
    const int* camid = (const int*)d_in[1];
    float* out = (float*)d_out;
    char* ws = (char*)d_ws;

    ushort_t* Fhi = (ushort_t*)ws;                               // 2 MB
    ushort_t* Flo = Fhi + (size_t)N * D;                         // 2 MB
    float* sq = (float*)(ws + 2 * (size_t)N * D * 2);            // 16 KB
    float* Rrow = sq + N;                                        // 16 KB
    float* rowloss = Rrow + N;                                   // 16 KB
    float4* partA = (float4*)(ws + 2 * (size_t)N * D * 2 + 3 * N * 4);  // 2 MB each
    float4* partB = partA + (size_t)PPARTS * N;
    float4* partC = partB + (size_t)PPARTS * N;

    prep_kernel<<<N, 64, 0, stream>>>(F, Fhi, Flo, sq, Rrow);
    fused_kernel<<<dim3(NCHUNK, NSTRIP), 256, 0, stream>>>(Fhi, Flo, sq, Rrow, camid,
                                                           partA, partB, partC);
    merge_kernel<<<N / 256, 256, 0, stream>>>(partA, partB, partC, Rrow, rowloss);
    final_reduce<<<1, 256, 0, stream>>>(rowloss, out);
}